// Round 4
// baseline (457.516 us; speedup 1.0000x reference)
//
#include <hip/hip_runtime.h>
#include <math.h>

#define NTOK 2048
#define DMODEL 1024
#define NHEAD 16
#define DHEAD 64

typedef _Float16 f16x8 __attribute__((ext_vector_type(8)));
typedef _Float16 f16x4 __attribute__((ext_vector_type(4)));
typedef float f32x4 __attribute__((ext_vector_type(4)));

__device__ __forceinline__ void split16(float x, _Float16& hi, _Float16& lo) {
    hi = (_Float16)x;
    lo = (_Float16)(x - (float)hi);
}

// 8B-aligned LDS vector helpers (P rows are 136B apart -> 8B aligned)
__device__ __forceinline__ f16x8 lds_ld8(const _Float16* p) {
    f16x8 r;
    *(f16x4*)&r       = *(const f16x4*)p;
    *((f16x4*)&r + 1) = *(const f16x4*)(p + 4);
    return r;
}

// ---------- prep: W[k][n] f32 -> Wt_hi/Wt_lo [n][k] f16, 4 matrices ----------
__global__ void __launch_bounds__(256) prep_w_kernel(
        const float* __restrict__ Wq, const float* __restrict__ Wk,
        const float* __restrict__ Wv, const float* __restrict__ Wo,
        _Float16* __restrict__ Wt) {
    __shared__ float T[32][33];
    const int z = blockIdx.z;
    const float* W = (z == 0) ? Wq : (z == 1) ? Wk : (z == 2) ? Wv : Wo;
    _Float16* Whi = Wt + (size_t)z * 2 * 1024 * 1024;
    _Float16* Wlo = Whi + (size_t)1024 * 1024;
    const int t = threadIdx.x;
    const int k0 = blockIdx.y * 32, n0 = blockIdx.x * 32;
    const int r = t >> 3, c4 = (t & 7) * 4;
    const float4 v = *(const float4*)(W + (size_t)(k0 + r) * DMODEL + n0 + c4);
    T[r][c4 + 0] = v.x; T[r][c4 + 1] = v.y; T[r][c4 + 2] = v.z; T[r][c4 + 3] = v.w;
    __syncthreads();
    f16x4 hv, lv;
#pragma unroll
    for (int j = 0; j < 4; ++j) {
        _Float16 h, l;
        split16(T[c4 + j][r], h, l);
        hv[j] = h; lv[j] = l;
    }
    *(f16x4*)(Whi + (size_t)(n0 + r) * DMODEL + k0 + c4) = hv;
    *(f16x4*)(Wlo + (size_t)(n0 + r) * DMODEL + k0 + c4) = lv;
}

// ---------- QKV projection: split-f16 MFMA GEMM ----------
__global__ void __launch_bounds__(256) qkv_mfma_kernel(
        const float* __restrict__ Aq, const float* __restrict__ Ak, const float* __restrict__ Av,
        const _Float16* __restrict__ Wt,
        const float* __restrict__ bq, const float* __restrict__ bk, const float* __restrict__ bv,
        _Float16* __restrict__ Qh, _Float16* __restrict__ Ql,
        _Float16* __restrict__ Kh, _Float16* __restrict__ Kl,
        _Float16* __restrict__ Vth, _Float16* __restrict__ Vtl) {
    __shared__ _Float16 Ah[128][40], Al[128][40], Bh[128][40], Bl[128][40];
    const int z = blockIdx.z;
    const float* A = (z == 0) ? Aq : (z == 1) ? Ak : Av;
    const _Float16* WH = Wt + (size_t)z * 2 * 1024 * 1024;
    const _Float16* WL = WH + (size_t)1024 * 1024;
    const float* bias = (z == 0) ? bq : (z == 1) ? bk : bv;

    const int t = threadIdx.x;
    const int l = t & 63, wid = t >> 6;
    const int lr = l & 15, lk = l >> 4;
    const int m0 = blockIdx.y * 128, n0 = blockIdx.x * 128;
    const int wm = (wid >> 1) * 64, wn = (wid & 1) * 64;

    f32x4 acc[4][4];
#pragma unroll
    for (int mi = 0; mi < 4; ++mi)
#pragma unroll
        for (int ni = 0; ni < 4; ++ni)
#pragma unroll
            for (int e = 0; e < 4; ++e) acc[mi][ni][e] = 0.f;

    for (int k0 = 0; k0 < DMODEL; k0 += 32) {
        __syncthreads();
#pragma unroll
        for (int p = 0; p < 4; ++p) {                    // A: f32 -> hi/lo f16
            const int idx = t + p * 256;
            const int r = idx >> 3, c4 = (idx & 7) * 4;
            const float4 v = *(const float4*)(A + (size_t)(m0 + r) * DMODEL + k0 + c4);
            f16x4 hv, lv; _Float16 h, lo;
            split16(v.x, h, lo); hv[0] = h; lv[0] = lo;
            split16(v.y, h, lo); hv[1] = h; lv[1] = lo;
            split16(v.z, h, lo); hv[2] = h; lv[2] = lo;
            split16(v.w, h, lo); hv[3] = h; lv[3] = lo;
            *(f16x4*)&Ah[r][c4] = hv;
            *(f16x4*)&Al[r][c4] = lv;
        }
#pragma unroll
        for (int p = 0; p < 2; ++p) {                    // B: prepped f16 direct
            const int idx = t + p * 256;
            const int r = idx >> 2, c8 = (idx & 3) * 8;
            *(f16x8*)&Bh[r][c8] = *(const f16x8*)(WH + (size_t)(n0 + r) * DMODEL + k0 + c8);
            *(f16x8*)&Bl[r][c8] = *(const f16x8*)(WL + (size_t)(n0 + r) * DMODEL + k0 + c8);
        }
        __syncthreads();

        f16x8 ah[4], al[4], bh[4], bl[4];
#pragma unroll
        for (int i = 0; i < 4; ++i) {
            ah[i] = *(f16x8*)&Ah[wm + i * 16 + lr][lk * 8];
            al[i] = *(f16x8*)&Al[wm + i * 16 + lr][lk * 8];
            bh[i] = *(f16x8*)&Bh[wn + i * 16 + lr][lk * 8];
            bl[i] = *(f16x8*)&Bl[wn + i * 16 + lr][lk * 8];
        }
#pragma unroll
        for (int mi = 0; mi < 4; ++mi)
#pragma unroll
            for (int ni = 0; ni < 4; ++ni) {
                acc[mi][ni] = __builtin_amdgcn_mfma_f32_16x16x32_f16(ah[mi], bh[ni], acc[mi][ni], 0, 0, 0);
                acc[mi][ni] = __builtin_amdgcn_mfma_f32_16x16x32_f16(ah[mi], bl[ni], acc[mi][ni], 0, 0, 0);
                acc[mi][ni] = __builtin_amdgcn_mfma_f32_16x16x32_f16(al[mi], bh[ni], acc[mi][ni], 0, 0, 0);
            }
    }

#pragma unroll
    for (int ni = 0; ni < 4; ++ni) {
        const int col = n0 + wn + ni * 16 + lr;
        const float bv_ = bias[col];
#pragma unroll
        for (int mi = 0; mi < 4; ++mi) {
            if (z == 2) {
                f16x4 hv, lv;
#pragma unroll
                for (int i = 0; i < 4; ++i) {
                    _Float16 h, lo;
                    split16(acc[mi][ni][i] + bv_, h, lo);
                    hv[i] = h; lv[i] = lo;
                }
                const int row = m0 + wm + mi * 16 + lk * 4;
                *(f16x4*)(Vth + (size_t)col * NTOK + row) = hv;
                *(f16x4*)(Vtl + (size_t)col * NTOK + row) = lv;
            } else {
#pragma unroll
                for (int i = 0; i < 4; ++i) {
                    const int row = m0 + wm + mi * 16 + lk * 4 + i;
                    float v = acc[mi][ni][i] + bv_;
                    if (z == 0) v *= 0.125f;
                    _Float16 h, lo;
                    split16(v, h, lo);
                    if (z == 0) { Qh[(size_t)row * DMODEL + col] = h; Ql[(size_t)row * DMODEL + col] = lo; }
                    else        { Kh[(size_t)row * DMODEL + col] = h; Kl[(size_t)row * DMODEL + col] = lo; }
                }
            }
        }
    }
}

// ---------- fused attention: barrier-free, K/V direct from L2, LDS only for P ----------
// Block 256 = 4 waves x 16 q-rows. Grid (32, 16). Zero __syncthreads.
__global__ void __launch_bounds__(256) attn_kernel(
        const _Float16* __restrict__ Qh, const _Float16* __restrict__ Ql,
        const _Float16* __restrict__ Kh, const _Float16* __restrict__ Kl,
        const _Float16* __restrict__ Vth, const _Float16* __restrict__ Vtl,
        float* __restrict__ attn, _Float16* __restrict__ Xh, _Float16* __restrict__ Xl) {
    __shared__ _Float16 P[4][2][16][68];   // wave-private P transpose buffer
    const int t = threadIdx.x;
    const int l = t & 63, wid = t >> 6;
    const int lr = l & 15, lk = l >> 4;
    const int h = blockIdx.y;
    const int rw = blockIdx.x * 64 + wid * 16;

    const _Float16* kh_base = Kh + (size_t)h * DHEAD;
    const _Float16* kl_base = Kl + (size_t)h * DHEAD;
    const _Float16* vh_base = Vth + (size_t)h * DHEAD * NTOK;
    const _Float16* vl_base = Vtl + (size_t)h * DHEAD * NTOK;

    f16x8 qh[2], qlo[2];
#pragma unroll
    for (int s = 0; s < 2; ++s) {
        qh[s]  = *(const f16x8*)(Qh + (size_t)(rw + lr) * DMODEL + h * DHEAD + s * 32 + lk * 8);
        qlo[s] = *(const f16x8*)(Ql + (size_t)(rw + lr) * DMODEL + h * DHEAD + s * 32 + lk * 8);
    }

    float m[4], lsum[4];
#pragma unroll
    for (int i = 0; i < 4; ++i) { m[i] = -1e30f; lsum[i] = 0.f; }

    // K-fragment loader (register tile)
    auto loadK = [&](int tt, f16x8 (&KH)[8], f16x8 (&KL)[8]) {
        const int j0 = tt * 64;
#pragma unroll
        for (int jt = 0; jt < 4; ++jt)
#pragma unroll
            for (int ks = 0; ks < 2; ++ks) {
                const size_t off = (size_t)(j0 + jt * 16 + lr) * DMODEL + ks * 32 + lk * 8;
                KH[jt * 2 + ks] = *(const f16x8*)(kh_base + off);
                KL[jt * 2 + ks] = *(const f16x8*)(kl_base + off);
            }
    };
    auto qkt = [&](const f16x8 (&KH)[8], const f16x8 (&KL)[8], f32x4 (&s)[4]) {
#pragma unroll
        for (int jt = 0; jt < 4; ++jt)
#pragma unroll
            for (int e = 0; e < 4; ++e) s[jt][e] = 0.f;
        __builtin_amdgcn_s_setprio(1);
#pragma unroll
        for (int jt = 0; jt < 4; ++jt)
#pragma unroll
            for (int ks = 0; ks < 2; ++ks) {
                s[jt] = __builtin_amdgcn_mfma_f32_16x16x32_f16(qh[ks],  KH[jt * 2 + ks], s[jt], 0, 0, 0);
                s[jt] = __builtin_amdgcn_mfma_f32_16x16x32_f16(qh[ks],  KL[jt * 2 + ks], s[jt], 0, 0, 0);
                s[jt] = __builtin_amdgcn_mfma_f32_16x16x32_f16(qlo[ks], KH[jt * 2 + ks], s[jt], 0, 0, 0);
            }
        __builtin_amdgcn_s_setprio(0);
    };
    auto stats = [&](const f32x4 (&s)[4]) {
#pragma unroll
        for (int i = 0; i < 4; ++i) {
            float v = fmaxf(fmaxf(s[0][i], s[1][i]), fmaxf(s[2][i], s[3][i]));
#pragma unroll
            for (int o = 1; o < 16; o <<= 1) v = fmaxf(v, __shfl_xor(v, o, 16));
            const float mn = fmaxf(m[i], v);
            float e = __expf(s[0][i] - mn) + __expf(s[1][i] - mn) +
                      __expf(s[2][i] - mn) + __expf(s[3][i] - mn);
#pragma unroll
            for (int o = 1; o < 16; o <<= 1) e += __shfl_xor(e, o, 16);
            lsum[i] = lsum[i] * __expf(m[i] - mn) + e;
            m[i] = mn;
        }
    };

    // ---- pass 1: stats only, register double-buffered K ----
    {
        f16x8 kha[8], kla[8], khb[8], klb[8];
        loadK(0, kha, kla);
        for (int tt = 0; tt < 32; tt += 2) {
            f32x4 s[4];
            if (tt + 1 < 32) loadK(tt + 1, khb, klb);
            qkt(kha, kla, s);
            stats(s);
            if (tt + 2 < 32) loadK(tt + 2, kha, kla);
            qkt(khb, klb, s);
            stats(s);
        }
    }

    float linv[4];
#pragma unroll
    for (int i = 0; i < 4; ++i) linv[i] = 1.0f / lsum[i];

    f32x4 x[4];
#pragma unroll
    for (int dt = 0; dt < 4; ++dt)
#pragma unroll
        for (int e = 0; e < 4; ++e) x[dt][e] = 0.f;

    // ---- pass 2: recompute scores, write attn (nontemporal), PV ----
    for (int tt = 0; tt < 32; ++tt) {
        const int j0 = tt * 64;
        f16x8 kh[8], kl[8];
        loadK(tt, kh, kl);

        // V fragments (independent of QK^T -> scheduler overlaps)
        f16x8 vh[8], vl[8];
#pragma unroll
        for (int dt = 0; dt < 4; ++dt)
#pragma unroll
            for (int ks = 0; ks < 2; ++ks) {
                const size_t off = (size_t)(dt * 16 + lr) * NTOK + j0 + ks * 32 + lk * 8;
                vh[dt * 2 + ks] = *(const f16x8*)(vh_base + off);
                vl[dt * 2 + ks] = *(const f16x8*)(vl_base + off);
            }

        f32x4 s[4];
        qkt(kh, kl, s);

#pragma unroll
        for (int jt = 0; jt < 4; ++jt)
#pragma unroll
            for (int i = 0; i < 4; ++i) {
                const float p = __expf(s[jt][i] - m[i]) * linv[i];
                __builtin_nontemporal_store(
                    p, attn + ((size_t)h * NTOK + rw + lk * 4 + i) * NTOK + j0 + jt * 16 + lr);
                _Float16 ph, pl;
                split16(p, ph, pl);
                P[wid][0][lk * 4 + i][jt * 16 + lr] = ph;
                P[wid][1][lk * 4 + i][jt * 16 + lr] = pl;
            }
        // wave-local read-back (lgkmcnt ordering; no barrier needed)
        f16x8 pah[2], pal[2];
#pragma unroll
        for (int ks = 0; ks < 2; ++ks) {
            pah[ks] = lds_ld8(&P[wid][0][lr][ks * 32 + lk * 8]);
            pal[ks] = lds_ld8(&P[wid][1][lr][ks * 32 + lk * 8]);
        }
        __builtin_amdgcn_s_setprio(1);
#pragma unroll
        for (int dt = 0; dt < 4; ++dt)
#pragma unroll
            for (int ks = 0; ks < 2; ++ks) {
                x[dt] = __builtin_amdgcn_mfma_f32_16x16x32_f16(pah[ks], vh[dt * 2 + ks], x[dt], 0, 0, 0);
                x[dt] = __builtin_amdgcn_mfma_f32_16x16x32_f16(pah[ks], vl[dt * 2 + ks], x[dt], 0, 0, 0);
                x[dt] = __builtin_amdgcn_mfma_f32_16x16x32_f16(pal[ks], vh[dt * 2 + ks], x[dt], 0, 0, 0);
            }
        __builtin_amdgcn_s_setprio(0);
    }

    // X epilogue -> hi/lo f16 for out-proj
#pragma unroll
    for (int dt = 0; dt < 4; ++dt)
#pragma unroll
        for (int i = 0; i < 4; ++i) {
            const int row = rw + lk * 4 + i;
            const int col = h * DHEAD + dt * 16 + lr;
            _Float16 hh, lo;
            split16(x[dt][i], hh, lo);
            Xh[(size_t)row * DMODEL + col] = hh;
            Xl[(size_t)row * DMODEL + col] = lo;
        }
}

// ---------- output projection: split-f16 MFMA GEMM, f32 epilogue ----------
__global__ void __launch_bounds__(256) out_mfma_kernel(
        const _Float16* __restrict__ Xh, const _Float16* __restrict__ Xl,
        const _Float16* __restrict__ WH, const _Float16* __restrict__ WL,
        const float* __restrict__ bo, float* __restrict__ out) {
    __shared__ _Float16 Ah[128][40], Al[128][40], Bh[128][40], Bl[128][40];
    const int t = threadIdx.x;
    const int l = t & 63, wid = t >> 6;
    const int lr = l & 15, lk = l >> 4;
    const int m0 = blockIdx.y * 128, n0 = blockIdx.x * 128;
    const int wm = (wid >> 1) * 64, wn = (wid & 1) * 64;

    f32x4 acc[4][4];
#pragma unroll
    for (int mi = 0; mi < 4; ++mi)
#pragma unroll
        for (int ni = 0; ni < 4; ++ni)
#pragma unroll
            for (int e = 0; e < 4; ++e) acc[mi][ni][e] = 0.f;

    for (int k0 = 0; k0 < DMODEL; k0 += 32) {
        __syncthreads();
#pragma unroll
        for (int p = 0; p < 2; ++p) {
            const int idx = t + p * 256;
            const int r = idx >> 2, c8 = (idx & 3) * 8;
            *(f16x8*)&Ah[r][c8] = *(const f16x8*)(Xh + (size_t)(m0 + r) * DMODEL + k0 + c8);
            *(f16x8*)&Al[r][c8] = *(const f16x8*)(Xl + (size_t)(m0 + r) * DMODEL + k0 + c8);
            *(f16x8*)&Bh[r][c8] = *(const f16x8*)(WH + (size_t)(n0 + r) * DMODEL + k0 + c8);
            *(f16x8*)&Bl[r][c8] = *(const f16x8*)(WL + (size_t)(n0 + r) * DMODEL + k0 + c8);
        }
        __syncthreads();

        f16x8 ah[4], al[4], bh[4], bl[4];
#pragma unroll
        for (int i = 0; i < 4; ++i) {
            ah[i] = *(f16x8*)&Ah[wm + i * 16 + lr][lk * 8];
            al[i] = *(f16x8*)&Al[wm + i * 16 + lr][lk * 8];
            bh[i] = *(f16x8*)&Bh[wn + i * 16 + lr][lk * 8];
            bl[i] = *(f16x8*)&Bl[wn + i * 16 + lr][lk * 8];
        }
#pragma unroll
        for (int mi = 0; mi < 4; ++mi)
#pragma unroll
            for (int ni = 0; ni < 4; ++ni) {
                acc[mi][ni] = __builtin_amdgcn_mfma_f32_16x16x32_f16(ah[mi], bh[ni], acc[mi][ni], 0, 0, 0);
                acc[mi][ni] = __builtin_amdgcn_mfma_f32_16x16x32_f16(ah[mi], bl[ni], acc[mi][ni], 0, 0, 0);
                acc[mi][ni] = __builtin_amdgcn_mfma_f32_16x16x32_f16(al[mi], bh[ni], acc[mi][ni], 0, 0, 0);
            }
    }

#pragma unroll
    for (int ni = 0; ni < 4; ++ni) {
        const int col = n0 + wn + ni * 16 + lr;
        const float bv_ = bo[col];
#pragma unroll
        for (int mi = 0; mi < 4; ++mi)
#pragma unroll
            for (int i = 0; i < 4; ++i) {
                const int row = m0 + wm + mi * 16 + lk * 4 + i;
                out[(size_t)row * DMODEL + col] = acc[mi][ni][i] + bv_;
            }
    }
}

extern "C" void kernel_launch(void* const* d_in, const int* in_sizes, int n_in,
                              void* d_out, int out_size, void* d_ws, size_t ws_size,
                              hipStream_t stream) {
    (void)in_sizes; (void)n_in; (void)out_size; (void)ws_size;
    const float* query = (const float*)d_in[0];
    const float* key_  = (const float*)d_in[1];
    const float* value = (const float*)d_in[2];
    const float* Wq = (const float*)d_in[3];
    const float* bq = (const float*)d_in[4];
    const float* Wk = (const float*)d_in[5];
    const float* bk = (const float*)d_in[6];
    const float* Wv = (const float*)d_in[7];
    const float* bv = (const float*)d_in[8];
    const float* Wo = (const float*)d_in[9];
    const float* bo = (const float*)d_in[10];

    float* out  = (float*)d_out;
    float* attn = out + (size_t)NTOK * DMODEL;

    const size_t MM = (size_t)1024 * 1024;
    _Float16* ws16 = (_Float16*)d_ws;          // total 24*MM halves = 48 MB
    _Float16* Wt  = ws16;                      // 8 planes (Wq,Wk,Wv,Wo x hi/lo)
    _Float16* Qh  = ws16 + 8 * MM;
    _Float16* Ql  = Qh  + 2 * MM;
    _Float16* Kh_ = Ql  + 2 * MM;
    _Float16* Kl_ = Kh_ + 2 * MM;
    _Float16* Vth = Kl_ + 2 * MM;
    _Float16* Vtl = Vth + 2 * MM;
    _Float16* Xh  = Vtl + 2 * MM;
    _Float16* Xl  = Xh  + 2 * MM;

    dim3 blk(256);
    prep_w_kernel<<<dim3(32, 32, 4), blk, 0, stream>>>(Wq, Wk, Wv, Wo, Wt);
    qkv_mfma_kernel<<<dim3(8, 16, 3), blk, 0, stream>>>(query, key_, value, Wt, bq, bk, bv,
                                                        Qh, Ql, Kh_, Kl_, Vth, Vtl);
    attn_kernel<<<dim3(32, 16), blk, 0, stream>>>(Qh, Ql, Kh_, Kl_, Vth, Vtl, attn, Xh, Xl);
    out_mfma_kernel<<<dim3(8, 16), blk, 0, stream>>>(Xh, Xl, Wt + 6 * MM, Wt + 7 * MM, bo, out);
}

// Round 6
// 276.904 us; speedup vs baseline: 1.6523x; 1.6523x over previous
//
#include <hip/hip_runtime.h>
#include <math.h>

#define NTOK 2048
#define DMODEL 1024
#define NHEAD 16
#define DHEAD 64
#define NCHUNK 2
#define CTILES (NTOK / 64 / NCHUNK)   // 16 tiles of 64 per chunk

typedef _Float16 f16x8 __attribute__((ext_vector_type(8)));
typedef _Float16 f16x4 __attribute__((ext_vector_type(4)));
typedef float f32x4 __attribute__((ext_vector_type(4)));

__device__ __forceinline__ void split16(float x, _Float16& hi, _Float16& lo) {
    hi = (_Float16)x;
    lo = (_Float16)(x - (float)hi);
}

// 8B-aligned LDS vector helpers (rows are 136B apart -> only 8B aligned; use b64 pairs)
__device__ __forceinline__ f16x8 lds_ld8(const _Float16* p) {
    f16x8 r;
    *(f16x4*)&r       = *(const f16x4*)p;
    *((f16x4*)&r + 1) = *(const f16x4*)(p + 4);
    return r;
}
__device__ __forceinline__ void lds_st8(_Float16* p, f16x8 v) {
    *(f16x4*)p       = *(f16x4*)&v;
    *(f16x4*)(p + 4) = *((f16x4*)&v + 1);
}

// ---------- prep: W[k][n] f32 -> Wt_hi/Wt_lo [n][k] f16, 4 matrices ----------
__global__ void __launch_bounds__(256) prep_w_kernel(
        const float* __restrict__ Wq, const float* __restrict__ Wk,
        const float* __restrict__ Wv, const float* __restrict__ Wo,
        _Float16* __restrict__ Wt) {
    __shared__ float T[32][33];
    const int z = blockIdx.z;
    const float* W = (z == 0) ? Wq : (z == 1) ? Wk : (z == 2) ? Wv : Wo;
    _Float16* Whi = Wt + (size_t)z * 2 * 1024 * 1024;
    _Float16* Wlo = Whi + (size_t)1024 * 1024;
    const int t = threadIdx.x;
    const int k0 = blockIdx.y * 32, n0 = blockIdx.x * 32;
    const int r = t >> 3, c4 = (t & 7) * 4;
    const float4 v = *(const float4*)(W + (size_t)(k0 + r) * DMODEL + n0 + c4);
    T[r][c4 + 0] = v.x; T[r][c4 + 1] = v.y; T[r][c4 + 2] = v.z; T[r][c4 + 3] = v.w;
    __syncthreads();
    f16x4 hv, lv;
#pragma unroll
    for (int j = 0; j < 4; ++j) {
        _Float16 h, l;
        split16(T[c4 + j][r], h, l);
        hv[j] = h; lv[j] = l;
    }
    *(f16x4*)(Whi + (size_t)(n0 + r) * DMODEL + k0 + c4) = hv;
    *(f16x4*)(Wlo + (size_t)(n0 + r) * DMODEL + k0 + c4) = lv;
}

// ---------- QKV projection: split-f16 MFMA GEMM, 64x128 tile ----------
__global__ void __launch_bounds__(256) qkv_mfma_kernel(
        const float* __restrict__ Aq, const float* __restrict__ Ak, const float* __restrict__ Av,
        const _Float16* __restrict__ Wt,
        const float* __restrict__ bq, const float* __restrict__ bk, const float* __restrict__ bv,
        _Float16* __restrict__ Qh, _Float16* __restrict__ Ql,
        _Float16* __restrict__ Kh, _Float16* __restrict__ Kl,
        _Float16* __restrict__ Vth, _Float16* __restrict__ Vtl) {
    __shared__ _Float16 Ah[64][40], Al[64][40], Bh[128][40], Bl[128][40];
    const int z = blockIdx.z;
    const float* A = (z == 0) ? Aq : (z == 1) ? Ak : Av;
    const _Float16* WH = Wt + (size_t)z * 2 * 1024 * 1024;
    const _Float16* WL = WH + (size_t)1024 * 1024;
    const float* bias = (z == 0) ? bq : (z == 1) ? bk : bv;

    const int t = threadIdx.x;
    const int l = t & 63, wid = t >> 6;
    const int lr = l & 15, lk = l >> 4;
    const int m0 = blockIdx.y * 64, n0 = blockIdx.x * 128;
    const int wm = (wid >> 1) * 32, wn = (wid & 1) * 64;

    f32x4 acc[2][4];
#pragma unroll
    for (int mi = 0; mi < 2; ++mi)
#pragma unroll
        for (int ni = 0; ni < 4; ++ni)
#pragma unroll
            for (int e = 0; e < 4; ++e) acc[mi][ni][e] = 0.f;

    for (int k0 = 0; k0 < DMODEL; k0 += 32) {
        __syncthreads();
#pragma unroll
        for (int p = 0; p < 2; ++p) {                    // A: f32 -> hi/lo f16 (64x32)
            const int idx = t + p * 256;
            const int r = idx >> 3, c4 = (idx & 7) * 4;
            const float4 v = *(const float4*)(A + (size_t)(m0 + r) * DMODEL + k0 + c4);
            f16x4 hv, lv; _Float16 h, lo;
            split16(v.x, h, lo); hv[0] = h; lv[0] = lo;
            split16(v.y, h, lo); hv[1] = h; lv[1] = lo;
            split16(v.z, h, lo); hv[2] = h; lv[2] = lo;
            split16(v.w, h, lo); hv[3] = h; lv[3] = lo;
            *(f16x4*)&Ah[r][c4] = hv;
            *(f16x4*)&Al[r][c4] = lv;
        }
#pragma unroll
        for (int p = 0; p < 2; ++p) {                    // B: prepped f16 (128x32)
            const int idx = t + p * 256;
            const int r = idx >> 2, c8 = (idx & 3) * 8;
            *(f16x8*)&Bh[r][c8] = *(const f16x8*)(WH + (size_t)(n0 + r) * DMODEL + k0 + c8);
            *(f16x8*)&Bl[r][c8] = *(const f16x8*)(WL + (size_t)(n0 + r) * DMODEL + k0 + c8);
        }
        __syncthreads();

        f16x8 ah[2], al[2], bh[4], bl[4];
#pragma unroll
        for (int i = 0; i < 2; ++i) {
            ah[i] = *(f16x8*)&Ah[wm + i * 16 + lr][lk * 8];
            al[i] = *(f16x8*)&Al[wm + i * 16 + lr][lk * 8];
        }
#pragma unroll
        for (int i = 0; i < 4; ++i) {
            bh[i] = *(f16x8*)&Bh[wn + i * 16 + lr][lk * 8];
            bl[i] = *(f16x8*)&Bl[wn + i * 16 + lr][lk * 8];
        }
#pragma unroll
        for (int mi = 0; mi < 2; ++mi)
#pragma unroll
            for (int ni = 0; ni < 4; ++ni) {
                acc[mi][ni] = __builtin_amdgcn_mfma_f32_16x16x32_f16(ah[mi], bh[ni], acc[mi][ni], 0, 0, 0);
                acc[mi][ni] = __builtin_amdgcn_mfma_f32_16x16x32_f16(ah[mi], bl[ni], acc[mi][ni], 0, 0, 0);
                acc[mi][ni] = __builtin_amdgcn_mfma_f32_16x16x32_f16(al[mi], bh[ni], acc[mi][ni], 0, 0, 0);
            }
    }

#pragma unroll
    for (int ni = 0; ni < 4; ++ni) {
        const int col = n0 + wn + ni * 16 + lr;
        const float bv_ = bias[col];
#pragma unroll
        for (int mi = 0; mi < 2; ++mi) {
            if (z == 2) {
                f16x4 hv, lv;
#pragma unroll
                for (int i = 0; i < 4; ++i) {
                    _Float16 h, lo;
                    split16(acc[mi][ni][i] + bv_, h, lo);
                    hv[i] = h; lv[i] = lo;
                }
                const int row = m0 + wm + mi * 16 + lk * 4;
                *(f16x4*)(Vth + (size_t)col * NTOK + row) = hv;
                *(f16x4*)(Vtl + (size_t)col * NTOK + row) = lv;
            } else {
#pragma unroll
                for (int i = 0; i < 4; ++i) {
                    const int row = m0 + wm + mi * 16 + lk * 4 + i;
                    float v = acc[mi][ni][i] + bv_;
                    if (z == 0) v *= 0.125f;
                    _Float16 h, lo;
                    split16(v, h, lo);
                    if (z == 0) { Qh[(size_t)row * DMODEL + col] = h; Ql[(size_t)row * DMODEL + col] = lo; }
                    else        { Kh[(size_t)row * DMODEL + col] = h; Kl[(size_t)row * DMODEL + col] = lo; }
                }
            }
        }
    }
}

// ---------- stats: partial (m,l) per row per KV-chunk ----------
// grid (32, 16, NCHUNK); LDS ping-pong K, 1 barrier/tile.
__global__ void __launch_bounds__(256, 4) stats_kernel(
        const _Float16* __restrict__ Qh, const _Float16* __restrict__ Ql,
        const _Float16* __restrict__ Kh, const _Float16* __restrict__ Kl,
        float* __restrict__ mpart, float* __restrict__ lpart) {
    __shared__ _Float16 KB[2][2][64][68];
    const int t = threadIdx.x;
    const int l = t & 63, wid = t >> 6;
    const int lr = l & 15, lk = l >> 4;
    const int h = blockIdx.y;
    const int z = blockIdx.z;
    const int rw = blockIdx.x * 64 + wid * 16;
    const int sjr = t >> 3, sc8 = (t & 7) * 8;
    const int jbase = z * CTILES * 64;

    f16x8 qh[2], qlo[2];
#pragma unroll
    for (int s = 0; s < 2; ++s) {
        qh[s]  = *(const f16x8*)(Qh + (size_t)(rw + lr) * DMODEL + h * DHEAD + s * 32 + lk * 8);
        qlo[s] = *(const f16x8*)(Ql + (size_t)(rw + lr) * DMODEL + h * DHEAD + s * 32 + lk * 8);
    }

    float m[4], lsum[4];
#pragma unroll
    for (int i = 0; i < 4; ++i) { m[i] = -1e30f; lsum[i] = 0.f; }

#pragma unroll
    for (int p = 0; p < 2; ++p) {
        const int jr = sjr + p * 32;
        lds_st8(&KB[0][0][jr][sc8], *(const f16x8*)(Kh + (size_t)(jbase + jr) * DMODEL + h * DHEAD + sc8));
        lds_st8(&KB[0][1][jr][sc8], *(const f16x8*)(Kl + (size_t)(jbase + jr) * DMODEL + h * DHEAD + sc8));
    }

    for (int it = 0; it < CTILES; ++it) {
        __syncthreads();
        const int cur = it & 1;
        if (it + 1 < CTILES) {
            const int j0n = jbase + (it + 1) * 64;
#pragma unroll
            for (int p = 0; p < 2; ++p) {
                const int jr = sjr + p * 32;
                lds_st8(&KB[cur ^ 1][0][jr][sc8], *(const f16x8*)(Kh + (size_t)(j0n + jr) * DMODEL + h * DHEAD + sc8));
                lds_st8(&KB[cur ^ 1][1][jr][sc8], *(const f16x8*)(Kl + (size_t)(j0n + jr) * DMODEL + h * DHEAD + sc8));
            }
        }
        f32x4 s[4];
#pragma unroll
        for (int jt = 0; jt < 4; ++jt)
#pragma unroll
            for (int e = 0; e < 4; ++e) s[jt][e] = 0.f;
        __builtin_amdgcn_s_setprio(1);
#pragma unroll
        for (int jt = 0; jt < 4; ++jt)
#pragma unroll
            for (int ks = 0; ks < 2; ++ks) {
                const f16x8 kh = lds_ld8(&KB[cur][0][jt * 16 + lr][ks * 32 + lk * 8]);
                const f16x8 kl = lds_ld8(&KB[cur][1][jt * 16 + lr][ks * 32 + lk * 8]);
                s[jt] = __builtin_amdgcn_mfma_f32_16x16x32_f16(qh[ks],  kh, s[jt], 0, 0, 0);
                s[jt] = __builtin_amdgcn_mfma_f32_16x16x32_f16(qh[ks],  kl, s[jt], 0, 0, 0);
                s[jt] = __builtin_amdgcn_mfma_f32_16x16x32_f16(qlo[ks], kh, s[jt], 0, 0, 0);
            }
        __builtin_amdgcn_s_setprio(0);
#pragma unroll
        for (int i = 0; i < 4; ++i) {
            float v = fmaxf(fmaxf(s[0][i], s[1][i]), fmaxf(s[2][i], s[3][i]));
#pragma unroll
            for (int o = 1; o < 16; o <<= 1) v = fmaxf(v, __shfl_xor(v, o, 16));
            const float mn = fmaxf(m[i], v);
            float e = __expf(s[0][i] - mn) + __expf(s[1][i] - mn) +
                      __expf(s[2][i] - mn) + __expf(s[3][i] - mn);
#pragma unroll
            for (int o = 1; o < 16; o <<= 1) e += __shfl_xor(e, o, 16);
            lsum[i] = lsum[i] * __expf(m[i] - mn) + e;
            m[i] = mn;
        }
    }

    if (lr == 0) {
#pragma unroll
        for (int i = 0; i < 4; ++i) {
            const int row = rw + lk * 4 + i;
            mpart[((size_t)z * NHEAD + h) * NTOK + row] = m[i];
            lpart[((size_t)z * NHEAD + h) * NTOK + row] = lsum[i];
        }
    }
}

// ---------- attn + PV: combine partials, write attn, per-chunk X partial ----------
// grid (32, 16, NCHUNK)
__global__ void __launch_bounds__(256, 4) attnpv_kernel(
        const _Float16* __restrict__ Qh, const _Float16* __restrict__ Ql,
        const _Float16* __restrict__ Kh, const _Float16* __restrict__ Kl,
        const _Float16* __restrict__ Vth, const _Float16* __restrict__ Vtl,
        const float* __restrict__ mpart, const float* __restrict__ lpart,
        float* __restrict__ attn, float* __restrict__ Xp0, float* __restrict__ Xp1) {
    __shared__ _Float16 KB[2][2][64][68];   // buf0: K then P-alias; buf1: V
    const int t = threadIdx.x;
    const int l = t & 63, wid = t >> 6;
    const int lr = l & 15, lk = l >> 4;
    const int h = blockIdx.y;
    const int z = blockIdx.z;
    const int rw = blockIdx.x * 64 + wid * 16;
    const int sjr = t >> 3, sc8 = (t & 7) * 8;
    float* __restrict__ Xout = (z == 0) ? Xp0 : Xp1;

    float m[4], linv[4];
#pragma unroll
    for (int i = 0; i < 4; ++i) {
        const int row = rw + lk * 4 + i;
        const float m0p = mpart[(size_t)h * NTOK + row];
        const float l0p = lpart[(size_t)h * NTOK + row];
        const float m1p = mpart[((size_t)NHEAD + h) * NTOK + row];
        const float l1p = lpart[((size_t)NHEAD + h) * NTOK + row];
        const float mg = fmaxf(m0p, m1p);
        const float lg = l0p * __expf(m0p - mg) + l1p * __expf(m1p - mg);
        m[i] = mg;
        linv[i] = 1.0f / lg;
    }

    f16x8 qh[2], qlo[2];
#pragma unroll
    for (int s = 0; s < 2; ++s) {
        qh[s]  = *(const f16x8*)(Qh + (size_t)(rw + lr) * DMODEL + h * DHEAD + s * 32 + lk * 8);
        qlo[s] = *(const f16x8*)(Ql + (size_t)(rw + lr) * DMODEL + h * DHEAD + s * 32 + lk * 8);
    }

    f32x4 x[4];
#pragma unroll
    for (int dt = 0; dt < 4; ++dt)
#pragma unroll
        for (int e = 0; e < 4; ++e) x[dt][e] = 0.f;

    for (int it = 0; it < CTILES; ++it) {
        const int j0 = (z * CTILES + it) * 64;
        __syncthreads();                       // prev PV reads done
#pragma unroll
        for (int p = 0; p < 2; ++p) {
            const int jr = sjr + p * 32;
            lds_st8(&KB[0][0][jr][sc8], *(const f16x8*)(Kh + (size_t)(j0 + jr) * DMODEL + h * DHEAD + sc8));
            lds_st8(&KB[0][1][jr][sc8], *(const f16x8*)(Kl + (size_t)(j0 + jr) * DMODEL + h * DHEAD + sc8));
            lds_st8(&KB[1][0][jr][sc8], *(const f16x8*)(Vth + (size_t)(h * DHEAD + jr) * NTOK + j0 + sc8));
            lds_st8(&KB[1][1][jr][sc8], *(const f16x8*)(Vtl + (size_t)(h * DHEAD + jr) * NTOK + j0 + sc8));
        }
        __syncthreads();

        f32x4 s[4];
#pragma unroll
        for (int jt = 0; jt < 4; ++jt)
#pragma unroll
            for (int e = 0; e < 4; ++e) s[jt][e] = 0.f;
        __builtin_amdgcn_s_setprio(1);
#pragma unroll
        for (int jt = 0; jt < 4; ++jt)
#pragma unroll
            for (int ks = 0; ks < 2; ++ks) {
                const f16x8 kh = lds_ld8(&KB[0][0][jt * 16 + lr][ks * 32 + lk * 8]);
                const f16x8 kl = lds_ld8(&KB[0][1][jt * 16 + lr][ks * 32 + lk * 8]);
                s[jt] = __builtin_amdgcn_mfma_f32_16x16x32_f16(qh[ks],  kh, s[jt], 0, 0, 0);
                s[jt] = __builtin_amdgcn_mfma_f32_16x16x32_f16(qh[ks],  kl, s[jt], 0, 0, 0);
                s[jt] = __builtin_amdgcn_mfma_f32_16x16x32_f16(qlo[ks], kh, s[jt], 0, 0, 0);
            }
        __builtin_amdgcn_s_setprio(0);
        __syncthreads();                       // all K reads done before P overwrites buf0

#pragma unroll
        for (int jt = 0; jt < 4; ++jt)
#pragma unroll
            for (int i = 0; i < 4; ++i) {
                const float p = __expf(s[jt][i] - m[i]) * linv[i];
                __builtin_nontemporal_store(
                    p, attn + ((size_t)h * NTOK + rw + lk * 4 + i) * NTOK + j0 + jt * 16 + lr);
                _Float16 ph, pl;
                split16(p, ph, pl);
                KB[0][0][wid * 16 + lk * 4 + i][jt * 16 + lr] = ph;
                KB[0][1][wid * 16 + lk * 4 + i][jt * 16 + lr] = pl;
            }
        // wave-local P read-back (lgkmcnt ordering; no barrier needed)
        f16x8 pah[2], pal[2];
#pragma unroll
        for (int ks = 0; ks < 2; ++ks) {
            pah[ks] = lds_ld8(&KB[0][0][wid * 16 + lr][ks * 32 + lk * 8]);
            pal[ks] = lds_ld8(&KB[0][1][wid * 16 + lr][ks * 32 + lk * 8]);
        }
        __builtin_amdgcn_s_setprio(1);
#pragma unroll
        for (int dt = 0; dt < 4; ++dt)
#pragma unroll
            for (int ks = 0; ks < 2; ++ks) {
                const f16x8 vh = lds_ld8(&KB[1][0][dt * 16 + lr][ks * 32 + lk * 8]);
                const f16x8 vl = lds_ld8(&KB[1][1][dt * 16 + lr][ks * 32 + lk * 8]);
                x[dt] = __builtin_amdgcn_mfma_f32_16x16x32_f16(pah[ks], vh, x[dt], 0, 0, 0);
                x[dt] = __builtin_amdgcn_mfma_f32_16x16x32_f16(pah[ks], vl, x[dt], 0, 0, 0);
                x[dt] = __builtin_amdgcn_mfma_f32_16x16x32_f16(pal[ks], vh, x[dt], 0, 0, 0);
            }
        __builtin_amdgcn_s_setprio(0);
    }

    // write this chunk's X partial (deterministic; out_mfma sums the two)
#pragma unroll
    for (int dt = 0; dt < 4; ++dt)
#pragma unroll
        for (int i = 0; i < 4; ++i) {
            const int row = rw + lk * 4 + i;
            const int col = h * DHEAD + dt * 16 + lr;
            Xout[(size_t)row * DMODEL + col] = x[dt][i];
        }
}

// ---------- output projection: A = Xp0+Xp1 (f32) -> split, 64x128 tile ----------
__global__ void __launch_bounds__(256) out_mfma_kernel(
        const float* __restrict__ Xp0, const float* __restrict__ Xp1,
        const _Float16* __restrict__ WH, const _Float16* __restrict__ WL,
        const float* __restrict__ bo, float* __restrict__ out) {
    __shared__ _Float16 Ah[64][40], Al[64][40], Bh[128][40], Bl[128][40];
    const int t = threadIdx.x;
    const int l = t & 63, wid = t >> 6;
    const int lr = l & 15, lk = l >> 4;
    const int m0 = blockIdx.y * 64, n0 = blockIdx.x * 128;
    const int wm = (wid >> 1) * 32, wn = (wid & 1) * 64;

    f32x4 acc[2][4];
#pragma unroll
    for (int mi = 0; mi < 2; ++mi)
#pragma unroll
        for (int ni = 0; ni < 4; ++ni)
#pragma unroll
            for (int e = 0; e < 4; ++e) acc[mi][ni][e] = 0.f;

    for (int k0 = 0; k0 < DMODEL; k0 += 32) {
        __syncthreads();
#pragma unroll
        for (int p = 0; p < 2; ++p) {
            const int idx = t + p * 256;
            const int r = idx >> 3, c4 = (idx & 7) * 4;
            const size_t off = (size_t)(m0 + r) * DMODEL + k0 + c4;
            const float4 v0 = *(const float4*)(Xp0 + off);
            const float4 v1 = *(const float4*)(Xp1 + off);
            f16x4 hv, lv; _Float16 h, lo;
            split16(v0.x + v1.x, h, lo); hv[0] = h; lv[0] = lo;
            split16(v0.y + v1.y, h, lo); hv[1] = h; lv[1] = lo;
            split16(v0.z + v1.z, h, lo); hv[2] = h; lv[2] = lo;
            split16(v0.w + v1.w, h, lo); hv[3] = h; lv[3] = lo;
            *(f16x4*)&Ah[r][c4] = hv;
            *(f16x4*)&Al[r][c4] = lv;
        }
#pragma unroll
        for (int p = 0; p < 2; ++p) {
            const int idx = t + p * 256;
            const int r = idx >> 2, c8 = (idx & 3) * 8;
            *(f16x8*)&Bh[r][c8] = *(const f16x8*)(WH + (size_t)(n0 + r) * DMODEL + k0 + c8);
            *(f16x8*)&Bl[r][c8] = *(const f16x8*)(WL + (size_t)(n0 + r) * DMODEL + k0 + c8);
        }
        __syncthreads();

        f16x8 ah[2], al[2], bh[4], bl[4];
#pragma unroll
        for (int i = 0; i < 2; ++i) {
            ah[i] = *(f16x8*)&Ah[wm + i * 16 + lr][lk * 8];
            al[i] = *(f16x8*)&Al[wm + i * 16 + lr][lk * 8];
        }
#pragma unroll
        for (int i = 0; i < 4; ++i) {
            bh[i] = *(f16x8*)&Bh[wn + i * 16 + lr][lk * 8];
            bl[i] = *(f16x8*)&Bl[wn + i * 16 + lr][lk * 8];
        }
#pragma unroll
        for (int mi = 0; mi < 2; ++mi)
#pragma unroll
            for (int ni = 0; ni < 4; ++ni) {
                acc[mi][ni] = __builtin_amdgcn_mfma_f32_16x16x32_f16(ah[mi], bh[ni], acc[mi][ni], 0, 0, 0);
                acc[mi][ni] = __builtin_amdgcn_mfma_f32_16x16x32_f16(ah[mi], bl[ni], acc[mi][ni], 0, 0, 0);
                acc[mi][ni] = __builtin_amdgcn_mfma_f32_16x16x32_f16(al[mi], bh[ni], acc[mi][ni], 0, 0, 0);
            }
    }

#pragma unroll
    for (int ni = 0; ni < 4; ++ni) {
        const int col = n0 + wn + ni * 16 + lr;
        const float bv_ = bo[col];
#pragma unroll
        for (int mi = 0; mi < 2; ++mi)
#pragma unroll
            for (int i = 0; i < 4; ++i) {
                const int row = m0 + wm + mi * 16 + lk * 4 + i;
                out[(size_t)row * DMODEL + col] = acc[mi][ni][i] + bv_;
            }
    }
}

extern "C" void kernel_launch(void* const* d_in, const int* in_sizes, int n_in,
                              void* d_out, int out_size, void* d_ws, size_t ws_size,
                              hipStream_t stream) {
    (void)in_sizes; (void)n_in; (void)out_size; (void)ws_size;
    const float* query = (const float*)d_in[0];
    const float* key_  = (const float*)d_in[1];
    const float* value = (const float*)d_in[2];
    const float* Wq = (const float*)d_in[3];
    const float* bq = (const float*)d_in[4];
    const float* Wk = (const float*)d_in[5];
    const float* bk = (const float*)d_in[6];
    const float* Wv = (const float*)d_in[7];
    const float* bv = (const float*)d_in[8];
    const float* Wo = (const float*)d_in[9];
    const float* bo = (const float*)d_in[10];

    float* out  = (float*)d_out;
    float* attn = out + (size_t)NTOK * DMODEL;

    const size_t MM = (size_t)1024 * 1024;
    _Float16* ws16 = (_Float16*)d_ws;          // 48 MB total
    _Float16* Wt  = ws16;                      // 8 planes (Wq,Wk,Wv,Wo x hi/lo), 16 MB
    _Float16* Qh  = ws16 + 8 * MM;             // 6 x 4 MB QKV planes
    _Float16* Ql  = Qh  + 2 * MM;
    _Float16* Kh_ = Ql  + 2 * MM;
    _Float16* Kl_ = Kh_ + 2 * MM;
    _Float16* Vth = Kl_ + 2 * MM;
    _Float16* Vtl = Vth + 2 * MM;

    // dead-after-qkv aliases: Xp0 over Wq/Wk planes; m/l partials over Wv hi plane
    float* Xp0   = (float*)ws16;                               // 8 MB over Wt[0..4MM)
    float* mpart = (float*)(ws16 + 4 * MM);                    // 256 KB over Wv_hi
    float* lpart = mpart + (size_t)NCHUNK * NHEAD * NTOK;      // 256 KB
    float* Xp1   = (float*)(ws16 + 20 * MM);                   // fresh 8 MB

    dim3 blk(256);
    prep_w_kernel<<<dim3(32, 32, 4), blk, 0, stream>>>(Wq, Wk, Wv, Wo, Wt);
    qkv_mfma_kernel<<<dim3(8, 32, 3), blk, 0, stream>>>(query, key_, value, Wt, bq, bk, bv,
                                                        Qh, Ql, Kh_, Kl_, Vth, Vtl);
    stats_kernel<<<dim3(32, 16, NCHUNK), blk, 0, stream>>>(Qh, Ql, Kh_, Kl_, mpart, lpart);
    attnpv_kernel<<<dim3(32, 16, NCHUNK), blk, 0, stream>>>(Qh, Ql, Kh_, Kl_, Vth, Vtl,
                                                            mpart, lpart, attn, Xp0, Xp1);
    out_mfma_kernel<<<dim3(8, 32), blk, 0, stream>>>(Xp0, Xp1, Wt + 6 * MM, Wt + 7 * MM, bo, out);
}

// Round 7
// 243.012 us; speedup vs baseline: 1.8827x; 1.1395x over previous
//
#include <hip/hip_runtime.h>
#include <math.h>

#define NTOK 2048
#define DMODEL 1024
#define NHEAD 16
#define DHEAD 64
#define NCH_S 4
#define NCH_A 2
#define TIL_S (NTOK / 64 / NCH_S)   // 8 tiles per stats chunk
#define TIL_A (NTOK / 64 / NCH_A)   // 16 tiles per attnpv chunk

typedef _Float16 f16x8 __attribute__((ext_vector_type(8)));
typedef _Float16 f16x4 __attribute__((ext_vector_type(4)));
typedef _Float16 f16x2 __attribute__((ext_vector_type(2)));
typedef float f32x4 __attribute__((ext_vector_type(4)));
typedef float f32x16 __attribute__((ext_vector_type(16)));

union U32H2 { f16x2 h; unsigned u; };
union U8 { f16x8 v; unsigned u[4]; };

__device__ __forceinline__ void split16(float x, _Float16& hi, _Float16& lo) {
    hi = (_Float16)x;
    lo = (_Float16)(x - (float)hi);
}
__device__ __forceinline__ unsigned packh(_Float16 a, _Float16 b) {
    U32H2 c; c.h = f16x2{a, b}; return c.u;
}

// ---------- prep: W[k][n] f32 -> Wt_hi/Wt_lo [n][k] f16, 4 matrices ----------
__global__ void __launch_bounds__(256) prep_w_kernel(
        const float* __restrict__ Wq, const float* __restrict__ Wk,
        const float* __restrict__ Wv, const float* __restrict__ Wo,
        _Float16* __restrict__ Wt) {
    __shared__ float T[32][33];
    const int z = blockIdx.z;
    const float* W = (z == 0) ? Wq : (z == 1) ? Wk : (z == 2) ? Wv : Wo;
    _Float16* Whi = Wt + (size_t)z * 2 * 1024 * 1024;
    _Float16* Wlo = Whi + (size_t)1024 * 1024;
    const int t = threadIdx.x;
    const int k0 = blockIdx.y * 32, n0 = blockIdx.x * 32;
    const int r = t >> 3, c4 = (t & 7) * 4;
    const float4 v = *(const float4*)(W + (size_t)(k0 + r) * DMODEL + n0 + c4);
    T[r][c4 + 0] = v.x; T[r][c4 + 1] = v.y; T[r][c4 + 2] = v.z; T[r][c4 + 3] = v.w;
    __syncthreads();
    f16x4 hv, lv;
#pragma unroll
    for (int j = 0; j < 4; ++j) {
        _Float16 h, l;
        split16(T[c4 + j][r], h, l);
        hv[j] = h; lv[j] = l;
    }
    *(f16x4*)(Whi + (size_t)(n0 + r) * DMODEL + k0 + c4) = hv;
    *(f16x4*)(Wlo + (size_t)(n0 + r) * DMODEL + k0 + c4) = lv;
}

// ---------- QKV projection: split-f16 MFMA GEMM, 64x128 tile (16x16 MFMA) ----------
__global__ void __launch_bounds__(256) qkv_mfma_kernel(
        const float* __restrict__ Aq, const float* __restrict__ Ak, const float* __restrict__ Av,
        const _Float16* __restrict__ Wt,
        const float* __restrict__ bq, const float* __restrict__ bk, const float* __restrict__ bv,
        _Float16* __restrict__ Qh, _Float16* __restrict__ Ql,
        _Float16* __restrict__ Kh, _Float16* __restrict__ Kl,
        _Float16* __restrict__ Vth, _Float16* __restrict__ Vtl) {
    __shared__ _Float16 Ah[64][40], Al[64][40], Bh[128][40], Bl[128][40];
    const int z = blockIdx.z;
    const float* A = (z == 0) ? Aq : (z == 1) ? Ak : Av;
    const _Float16* WH = Wt + (size_t)z * 2 * 1024 * 1024;
    const _Float16* WL = WH + (size_t)1024 * 1024;
    const float* bias = (z == 0) ? bq : (z == 1) ? bk : bv;

    const int t = threadIdx.x;
    const int l = t & 63, wid = t >> 6;
    const int lr = l & 15, lk = l >> 4;
    const int m0 = blockIdx.y * 64, n0 = blockIdx.x * 128;
    const int wm = (wid >> 1) * 32, wn = (wid & 1) * 64;

    f32x4 acc[2][4];
#pragma unroll
    for (int mi = 0; mi < 2; ++mi)
#pragma unroll
        for (int ni = 0; ni < 4; ++ni)
#pragma unroll
            for (int e = 0; e < 4; ++e) acc[mi][ni][e] = 0.f;

    for (int k0 = 0; k0 < DMODEL; k0 += 32) {
        __syncthreads();
#pragma unroll
        for (int p = 0; p < 2; ++p) {
            const int idx = t + p * 256;
            const int r = idx >> 3, c4 = (idx & 7) * 4;
            const float4 v = *(const float4*)(A + (size_t)(m0 + r) * DMODEL + k0 + c4);
            f16x4 hv, lv; _Float16 h, lo;
            split16(v.x, h, lo); hv[0] = h; lv[0] = lo;
            split16(v.y, h, lo); hv[1] = h; lv[1] = lo;
            split16(v.z, h, lo); hv[2] = h; lv[2] = lo;
            split16(v.w, h, lo); hv[3] = h; lv[3] = lo;
            *(f16x4*)&Ah[r][c4] = hv;
            *(f16x4*)&Al[r][c4] = lv;
        }
#pragma unroll
        for (int p = 0; p < 2; ++p) {
            const int idx = t + p * 256;
            const int r = idx >> 2, c8 = (idx & 3) * 8;
            *(f16x8*)&Bh[r][c8] = *(const f16x8*)(WH + (size_t)(n0 + r) * DMODEL + k0 + c8);
            *(f16x8*)&Bl[r][c8] = *(const f16x8*)(WL + (size_t)(n0 + r) * DMODEL + k0 + c8);
        }
        __syncthreads();

        f16x8 ah[2], al[2], bh[4], bl[4];
#pragma unroll
        for (int i = 0; i < 2; ++i) {
            ah[i] = *(f16x8*)&Ah[wm + i * 16 + lr][lk * 8];
            al[i] = *(f16x8*)&Al[wm + i * 16 + lr][lk * 8];
        }
#pragma unroll
        for (int i = 0; i < 4; ++i) {
            bh[i] = *(f16x8*)&Bh[wn + i * 16 + lr][lk * 8];
            bl[i] = *(f16x8*)&Bl[wn + i * 16 + lr][lk * 8];
        }
#pragma unroll
        for (int mi = 0; mi < 2; ++mi)
#pragma unroll
            for (int ni = 0; ni < 4; ++ni) {
                acc[mi][ni] = __builtin_amdgcn_mfma_f32_16x16x32_f16(ah[mi], bh[ni], acc[mi][ni], 0, 0, 0);
                acc[mi][ni] = __builtin_amdgcn_mfma_f32_16x16x32_f16(ah[mi], bl[ni], acc[mi][ni], 0, 0, 0);
                acc[mi][ni] = __builtin_amdgcn_mfma_f32_16x16x32_f16(al[mi], bh[ni], acc[mi][ni], 0, 0, 0);
            }
    }

#pragma unroll
    for (int ni = 0; ni < 4; ++ni) {
        const int col = n0 + wn + ni * 16 + lr;
        const float bv_ = bias[col];
#pragma unroll
        for (int mi = 0; mi < 2; ++mi) {
            if (z == 2) {
                f16x4 hv, lv;
#pragma unroll
                for (int i = 0; i < 4; ++i) {
                    _Float16 h, lo;
                    split16(acc[mi][ni][i] + bv_, h, lo);
                    hv[i] = h; lv[i] = lo;
                }
                const int row = m0 + wm + mi * 16 + lk * 4;
                *(f16x4*)(Vth + (size_t)col * NTOK + row) = hv;
                *(f16x4*)(Vtl + (size_t)col * NTOK + row) = lv;
            } else {
#pragma unroll
                for (int i = 0; i < 4; ++i) {
                    const int row = m0 + wm + mi * 16 + lk * 4 + i;
                    float v = acc[mi][ni][i] + bv_;
                    if (z == 0) v *= 0.125f;
                    _Float16 h, lo;
                    split16(v, h, lo);
                    if (z == 0) { Qh[(size_t)row * DMODEL + col] = h; Ql[(size_t)row * DMODEL + col] = lo; }
                    else        { Kh[(size_t)row * DMODEL + col] = h; Kl[(size_t)row * DMODEL + col] = lo; }
                }
            }
        }
    }
}

// ---------- stats: l = sum exp(s) per row, 32x32 swapped QKT, no max ----------
// grid (16, 16, NCH_S); block 256 = 4 waves x 32 q rows.
__global__ void __launch_bounds__(256, 4) stats_kernel(
        const _Float16* __restrict__ Qh, const _Float16* __restrict__ Ql,
        const _Float16* __restrict__ Kh, const _Float16* __restrict__ Kl,
        float* __restrict__ lpart) {
    __shared__ _Float16 KB[2][2][64][64];
    const int t = threadIdx.x, l = t & 63, w = t >> 6, q = l & 31, h = l >> 5;
    const int hh = blockIdx.y, z = blockIdx.z;
    const int rw = blockIdx.x * 128 + w * 32;
    const int sr = t >> 3, sc = t & 7;

    f16x8 qbh[4], qbl[4];
#pragma unroll
    for (int s = 0; s < 4; ++s) {
        const size_t off = (size_t)(rw + q) * DMODEL + hh * DHEAD + s * 16 + h * 8;
        qbh[s] = *(const f16x8*)(Qh + off);
        qbl[s] = *(const f16x8*)(Ql + off);
    }

    float lsum = 0.f;
    {
        const int j0 = z * TIL_S * 64;
#pragma unroll
        for (int p = 0; p < 2; ++p) {
            const int r = sr + p * 32; const int cs = (sc ^ (r & 7)) * 8;
            *(f16x8*)&KB[0][0][r][cs] = *(const f16x8*)(Kh + (size_t)(j0 + r) * DMODEL + hh * DHEAD + sc * 8);
            *(f16x8*)&KB[0][1][r][cs] = *(const f16x8*)(Kl + (size_t)(j0 + r) * DMODEL + hh * DHEAD + sc * 8);
        }
    }
    for (int it = 0; it < TIL_S; ++it) {
        __syncthreads();
        const int cur = it & 1;
        if (it + 1 < TIL_S) {
            const int j0 = (z * TIL_S + it + 1) * 64;
#pragma unroll
            for (int p = 0; p < 2; ++p) {
                const int r = sr + p * 32; const int cs = (sc ^ (r & 7)) * 8;
                *(f16x8*)&KB[cur ^ 1][0][r][cs] = *(const f16x8*)(Kh + (size_t)(j0 + r) * DMODEL + hh * DHEAD + sc * 8);
                *(f16x8*)&KB[cur ^ 1][1][r][cs] = *(const f16x8*)(Kl + (size_t)(j0 + r) * DMODEL + hh * DHEAD + sc * 8);
            }
        }
#pragma unroll
        for (int kb = 0; kb < 2; ++kb) {
            f32x16 c;
#pragma unroll
            for (int r = 0; r < 16; ++r) c[r] = 0.f;
            __builtin_amdgcn_s_setprio(1);
#pragma unroll
            for (int s = 0; s < 4; ++s) {
                const int rk = kb * 32 + q; const int cc = ((2 * s + h) ^ (rk & 7)) * 8;
                const f16x8 ah = *(f16x8*)&KB[cur][0][rk][cc];
                const f16x8 al = *(f16x8*)&KB[cur][1][rk][cc];
                c = __builtin_amdgcn_mfma_f32_32x32x16_f16(ah, qbh[s], c, 0, 0, 0);
                c = __builtin_amdgcn_mfma_f32_32x32x16_f16(ah, qbl[s], c, 0, 0, 0);
                c = __builtin_amdgcn_mfma_f32_32x32x16_f16(al, qbh[s], c, 0, 0, 0);
            }
            __builtin_amdgcn_s_setprio(0);
#pragma unroll
            for (int r = 0; r < 16; ++r) lsum += __expf(c[r]);
        }
    }
    lsum += __shfl_xor(lsum, 32);
    if (h == 0) lpart[((size_t)z * NHEAD + hh) * NTOK + rw + q] = lsum;
}

// ---------- attn + PV: 32x32 swapped QKT, in-register P exchange, no LDS P ----------
// grid (16, 16, NCH_A); block 256 = 4 waves x 32 q rows.
__global__ void __launch_bounds__(256, 2) attnpv_kernel(
        const _Float16* __restrict__ Qh, const _Float16* __restrict__ Ql,
        const _Float16* __restrict__ Kh, const _Float16* __restrict__ Kl,
        const _Float16* __restrict__ Vth, const _Float16* __restrict__ Vtl,
        const float* __restrict__ lpart,
        float* __restrict__ attn, float* __restrict__ Xp0, float* __restrict__ Xp1) {
    __shared__ _Float16 KB[2][2][64][64];
    __shared__ _Float16 VB[2][2][64][64];
    const int t = threadIdx.x, l = t & 63, w = t >> 6, q = l & 31, h = l >> 5;
    const int hh = blockIdx.y, z = blockIdx.z;
    const int rw = blockIdx.x * 128 + w * 32;
    const int sr = t >> 3, sc = t & 7;
    const int qrow = rw + q;

    float lsum = 0.f;
#pragma unroll
    for (int zz = 0; zz < NCH_S; ++zz) lsum += lpart[((size_t)zz * NHEAD + hh) * NTOK + qrow];
    const float linv = 1.f / lsum;

    f16x8 qbh[4], qbl[4];
#pragma unroll
    for (int s = 0; s < 4; ++s) {
        const size_t off = (size_t)qrow * DMODEL + hh * DHEAD + s * 16 + h * 8;
        qbh[s] = *(const f16x8*)(Qh + off);
        qbl[s] = *(const f16x8*)(Ql + off);
    }

    f32x16 x0, x1;
#pragma unroll
    for (int r = 0; r < 16; ++r) { x0[r] = 0.f; x1[r] = 0.f; }

    auto stage = [&](int buf, int j0) {
#pragma unroll
        for (int p = 0; p < 2; ++p) {
            const int r = sr + p * 32; const int cs = (sc ^ (r & 7)) * 8;
            *(f16x8*)&KB[buf][0][r][cs] = *(const f16x8*)(Kh + (size_t)(j0 + r) * DMODEL + hh * DHEAD + sc * 8);
            *(f16x8*)&KB[buf][1][r][cs] = *(const f16x8*)(Kl + (size_t)(j0 + r) * DMODEL + hh * DHEAD + sc * 8);
            *(f16x8*)&VB[buf][0][r][cs] = *(const f16x8*)(Vth + (size_t)(hh * DHEAD + r) * NTOK + j0 + sc * 8);
            *(f16x8*)&VB[buf][1][r][cs] = *(const f16x8*)(Vtl + (size_t)(hh * DHEAD + r) * NTOK + j0 + sc * 8);
        }
    };
    stage(0, z * TIL_A * 64);

    for (int it = 0; it < TIL_A; ++it) {
        const int j0 = (z * TIL_A + it) * 64;
        __syncthreads();
        const int cur = it & 1;
        if (it + 1 < TIL_A) stage(cur ^ 1, (z * TIL_A + it + 1) * 64);

#pragma unroll
        for (int kb = 0; kb < 2; ++kb) {
            f32x16 c;
#pragma unroll
            for (int r = 0; r < 16; ++r) c[r] = 0.f;
            __builtin_amdgcn_s_setprio(1);
#pragma unroll
            for (int s = 0; s < 4; ++s) {
                const int rk = kb * 32 + q; const int cc = ((2 * s + h) ^ (rk & 7)) * 8;
                const f16x8 ah = *(f16x8*)&KB[cur][0][rk][cc];
                const f16x8 al = *(f16x8*)&KB[cur][1][rk][cc];
                c = __builtin_amdgcn_mfma_f32_32x32x16_f16(ah, qbh[s], c, 0, 0, 0);
                c = __builtin_amdgcn_mfma_f32_32x32x16_f16(ah, qbl[s], c, 0, 0, 0);
                c = __builtin_amdgcn_mfma_f32_32x32x16_f16(al, qbh[s], c, 0, 0, 0);
            }
            __builtin_amdgcn_s_setprio(0);

            float p[16];
#pragma unroll
            for (int r = 0; r < 16; ++r) p[r] = __expf(c[r]) * linv;

            const int kbase = j0 + kb * 32;
#pragma unroll
            for (int i = 0; i < 4; ++i) {
                const float4 st = make_float4(p[4 * i], p[4 * i + 1], p[4 * i + 2], p[4 * i + 3]);
                *(float4*)(attn + ((size_t)hh * NTOK + qrow) * NTOK + kbase + 8 * i + 4 * h) = st;
            }

            _Float16 hf[16], lf[16];
#pragma unroll
            for (int r = 0; r < 16; ++r) {
                hf[r] = (_Float16)p[r];
                lf[r] = (_Float16)(p[r] - (float)hf[r]);
            }
            unsigned ph[8], pl[8];
#pragma unroll
            for (int i = 0; i < 8; ++i) {
                ph[i] = packh(hf[2 * i], hf[2 * i + 1]);
                pl[i] = packh(lf[2 * i], lf[2 * i + 1]);
            }

#pragma unroll
            for (int ss = 0; ss < 2; ++ss) {
                const int b = 4 * ss;
                // lane h=0 sends pk[b+2..b+3] (k 8..11-equiv), h=1 sends pk[b..b+1]
                const unsigned eh0 = __shfl_xor(h ? ph[b + 0] : ph[b + 2], 32);
                const unsigned eh1 = __shfl_xor(h ? ph[b + 1] : ph[b + 3], 32);
                const unsigned el0 = __shfl_xor(h ? pl[b + 0] : pl[b + 2], 32);
                const unsigned el1 = __shfl_xor(h ? pl[b + 1] : pl[b + 3], 32);
                U8 pah, pal;
                pah.u[0] = h ? eh0 : ph[b + 0]; pah.u[1] = h ? eh1 : ph[b + 1];
                pah.u[2] = h ? ph[b + 2] : eh0; pah.u[3] = h ? ph[b + 3] : eh1;
                pal.u[0] = h ? el0 : pl[b + 0]; pal.u[1] = h ? el1 : pl[b + 1];
                pal.u[2] = h ? pl[b + 2] : el0; pal.u[3] = h ? pl[b + 3] : el1;
                const int ks = kb * 2 + ss;
                __builtin_amdgcn_s_setprio(1);
                {
                    const int rd0 = q; const int cv0 = ((2 * ks + h) ^ (rd0 & 7)) * 8;
                    const f16x8 vh = *(f16x8*)&VB[cur][0][rd0][cv0];
                    const f16x8 vl = *(f16x8*)&VB[cur][1][rd0][cv0];
                    x0 = __builtin_amdgcn_mfma_f32_32x32x16_f16(pah.v, vh, x0, 0, 0, 0);
                    x0 = __builtin_amdgcn_mfma_f32_32x32x16_f16(pah.v, vl, x0, 0, 0, 0);
                    x0 = __builtin_amdgcn_mfma_f32_32x32x16_f16(pal.v, vh, x0, 0, 0, 0);
                }
                {
                    const int rd1 = 32 + q; const int cv1 = ((2 * ks + h) ^ (rd1 & 7)) * 8;
                    const f16x8 vh = *(f16x8*)&VB[cur][0][rd1][cv1];
                    const f16x8 vl = *(f16x8*)&VB[cur][1][rd1][cv1];
                    x1 = __builtin_amdgcn_mfma_f32_32x32x16_f16(pah.v, vh, x1, 0, 0, 0);
                    x1 = __builtin_amdgcn_mfma_f32_32x32x16_f16(pah.v, vl, x1, 0, 0, 0);
                    x1 = __builtin_amdgcn_mfma_f32_32x32x16_f16(pal.v, vh, x1, 0, 0, 0);
                }
                __builtin_amdgcn_s_setprio(0);
            }
        }
    }

    float* __restrict__ Xout = z ? Xp1 : Xp0;
#pragma unroll
    for (int r = 0; r < 16; ++r) {
        const int qloc = (r & 3) + 8 * (r >> 2) + 4 * h;
        Xout[(size_t)(rw + qloc) * DMODEL + hh * DHEAD + q]      = x0[r];
        Xout[(size_t)(rw + qloc) * DMODEL + hh * DHEAD + 32 + q] = x1[r];
    }
}

// ---------- output projection: A = Xp0+Xp1 (f32) -> split, 64x128 tile ----------
__global__ void __launch_bounds__(256) out_mfma_kernel(
        const float* __restrict__ Xp0, const float* __restrict__ Xp1,
        const _Float16* __restrict__ WH, const _Float16* __restrict__ WL,
        const float* __restrict__ bo, float* __restrict__ out) {
    __shared__ _Float16 Ah[64][40], Al[64][40], Bh[128][40], Bl[128][40];
    const int t = threadIdx.x;
    const int l = t & 63, wid = t >> 6;
    const int lr = l & 15, lk = l >> 4;
    const int m0 = blockIdx.y * 64, n0 = blockIdx.x * 128;
    const int wm = (wid >> 1) * 32, wn = (wid & 1) * 64;

    f32x4 acc[2][4];
#pragma unroll
    for (int mi = 0; mi < 2; ++mi)
#pragma unroll
        for (int ni = 0; ni < 4; ++ni)
#pragma unroll
            for (int e = 0; e < 4; ++e) acc[mi][ni][e] = 0.f;

    for (int k0 = 0; k0 < DMODEL; k0 += 32) {
        __syncthreads();
#pragma unroll
        for (int p = 0; p < 2; ++p) {
            const int idx = t + p * 256;
            const int r = idx >> 3, c4 = (idx & 7) * 4;
            const size_t off = (size_t)(m0 + r) * DMODEL + k0 + c4;
            const float4 v0 = *(const float4*)(Xp0 + off);
            const float4 v1 = *(const float4*)(Xp1 + off);
            f16x4 hv, lv; _Float16 h, lo;
            split16(v0.x + v1.x, h, lo); hv[0] = h; lv[0] = lo;
            split16(v0.y + v1.y, h, lo); hv[1] = h; lv[1] = lo;
            split16(v0.z + v1.z, h, lo); hv[2] = h; lv[2] = lo;
            split16(v0.w + v1.w, h, lo); hv[3] = h; lv[3] = lo;
            *(f16x4*)&Ah[r][c4] = hv;
            *(f16x4*)&Al[r][c4] = lv;
        }
#pragma unroll
        for (int p = 0; p < 2; ++p) {
            const int idx = t + p * 256;
            const int r = idx >> 2, c8 = (idx & 3) * 8;
            *(f16x8*)&Bh[r][c8] = *(const f16x8*)(WH + (size_t)(n0 + r) * DMODEL + k0 + c8);
            *(f16x8*)&Bl[r][c8] = *(const f16x8*)(WL + (size_t)(n0 + r) * DMODEL + k0 + c8);
        }
        __syncthreads();

        f16x8 ah[2], al[2], bh[4], bl[4];
#pragma unroll
        for (int i = 0; i < 2; ++i) {
            ah[i] = *(f16x8*)&Ah[wm + i * 16 + lr][lk * 8];
            al[i] = *(f16x8*)&Al[wm + i * 16 + lr][lk * 8];
        }
#pragma unroll
        for (int i = 0; i < 4; ++i) {
            bh[i] = *(f16x8*)&Bh[wn + i * 16 + lr][lk * 8];
            bl[i] = *(f16x8*)&Bl[wn + i * 16 + lr][lk * 8];
        }
#pragma unroll
        for (int mi = 0; mi < 2; ++mi)
#pragma unroll
            for (int ni = 0; ni < 4; ++ni) {
                acc[mi][ni] = __builtin_amdgcn_mfma_f32_16x16x32_f16(ah[mi], bh[ni], acc[mi][ni], 0, 0, 0);
                acc[mi][ni] = __builtin_amdgcn_mfma_f32_16x16x32_f16(ah[mi], bl[ni], acc[mi][ni], 0, 0, 0);
                acc[mi][ni] = __builtin_amdgcn_mfma_f32_16x16x32_f16(al[mi], bh[ni], acc[mi][ni], 0, 0, 0);
            }
    }

#pragma unroll
    for (int ni = 0; ni < 4; ++ni) {
        const int col = n0 + wn + ni * 16 + lr;
        const float bv_ = bo[col];
#pragma unroll
        for (int mi = 0; mi < 2; ++mi)
#pragma unroll
            for (int i = 0; i < 4; ++i) {
                const int row = m0 + wm + mi * 16 + lk * 4 + i;
                out[(size_t)row * DMODEL + col] = acc[mi][ni][i] + bv_;
            }
    }
}

extern "C" void kernel_launch(void* const* d_in, const int* in_sizes, int n_in,
                              void* d_out, int out_size, void* d_ws, size_t ws_size,
                              hipStream_t stream) {
    (void)in_sizes; (void)n_in; (void)out_size; (void)ws_size;
    const float* query = (const float*)d_in[0];
    const float* key_  = (const float*)d_in[1];
    const float* value = (const float*)d_in[2];
    const float* Wq = (const float*)d_in[3];
    const float* bq = (const float*)d_in[4];
    const float* Wk = (const float*)d_in[5];
    const float* bk = (const float*)d_in[6];
    const float* Wv = (const float*)d_in[7];
    const float* bv = (const float*)d_in[8];
    const float* Wo = (const float*)d_in[9];
    const float* bo = (const float*)d_in[10];

    float* out  = (float*)d_out;
    float* attn = out + (size_t)NTOK * DMODEL;

    const size_t MM = (size_t)1024 * 1024;
    _Float16* ws16 = (_Float16*)d_ws;          // 48 MB total
    _Float16* Wt  = ws16;                      // 8 planes (Wq,Wk,Wv,Wo x hi/lo), 16 MB
    _Float16* Qh  = ws16 + 8 * MM;             // 6 x 4 MB QKV planes
    _Float16* Ql  = Qh  + 2 * MM;
    _Float16* Kh_ = Ql  + 2 * MM;
    _Float16* Kl_ = Kh_ + 2 * MM;
    _Float16* Vth = Kl_ + 2 * MM;
    _Float16* Vtl = Vth + 2 * MM;

    // dead-after-qkv aliases: Xp0 over Wq/Wk planes; lpart over Wv hi plane
    float* Xp0   = (float*)ws16;                               // 8 MB over Wt[0..4MM)
    float* lpart = (float*)(ws16 + 4 * MM);                    // 512 KB over Wv_hi
    float* Xp1   = (float*)(ws16 + 20 * MM);                   // fresh 8 MB

    dim3 blk(256);
    prep_w_kernel<<<dim3(32, 32, 4), blk, 0, stream>>>(Wq, Wk, Wv, Wo, Wt);
    qkv_mfma_kernel<<<dim3(8, 32, 3), blk, 0, stream>>>(query, key_, value, Wt, bq, bk, bv,
                                                        Qh, Ql, Kh_, Kl_, Vth, Vtl);
    stats_kernel<<<dim3(16, 16, NCH_S), blk, 0, stream>>>(Qh, Ql, Kh_, Kl_, lpart);
    attnpv_kernel<<<dim3(16, 16, NCH_A), blk, 0, stream>>>(Qh, Ql, Kh_, Kl_, Vth, Vtl,
                                                           lpart, attn, Xp0, Xp1);
    out_mfma_kernel<<<dim3(8, 32), blk, 0, stream>>>(Xp0, Xp1, Wt + 6 * MM, Wt + 7 * MM, bo, out);
}